// Round 1
// 198.092 us; speedup vs baseline: 1.0219x; 1.0219x over previous
//
#include <hip/hip_runtime.h>
#include <hip/hip_bf16.h>

#define LLEN 512
#define SLEN 64
#define EMBD 16
#define EE 48
#define GG 4
#define NHH 8
#define KDD 4
#define INDIM 224
#define H1D 200
#define H2D 80
#define CHUNK 128
#define PXE 52   // row stride: 48 data + 4 selector floats
#define NT 512   // 8 waves/block; 4 blocks/CU (LDS 36.9KB) -> 32 waves/CU

__device__ __forceinline__ float bf2f(unsigned short u) {
    union { unsigned int i; float f; } v; v.i = ((unsigned int)u) << 16; return v.f;
}

template<bool BF16>
__device__ __forceinline__ float ldf(const void* p, int i) {
    if constexpr (BF16) return bf2f(((const unsigned short*)p)[i]);
    else                return ((const float*)p)[i];
}

template<bool BF16>
__device__ __forceinline__ float4 ld4(const void* p, int i4) {
    if constexpr (BF16) {
        ushort4 u = ((const ushort4*)p)[i4 >> 2];
        return make_float4(bf2f(u.x), bf2f(u.y), bf2f(u.z), bf2f(u.w));
    } else {
        return ((const float4*)p)[i4 >> 2];
    }
}

struct Pool {
    float buf[CHUNK * PXE + 16];   // chunk rows (48 data + 4 sel) / attention / MLP scratch
    float part[8][GG][EE];         // [wave][g][e] partial selected-bucket sums
    float hf[12 * EE];             // H transposed fp32: hf[j*48+e] = H[e][j]
    float feat[INDIM];
    float q[NHH * KDD];
    float red[128];
    int   pcw[8][2];               // per-wave counts: wave w -> groups (w>>2)*2 + {0,1}
    int   icode[GG];
    int   len;
    float mu, rstd;
};

template<bool BF16>
__device__ void sdim_body(Pool& P,
    const int* uid, const int* ut1, const int* ut2, const int* ut3, const int* ut4,
    const int* lb_g, const int* lb_s, const int* lb_c,
    const int* lt_g, const int* lt_s, const int* lt_c,
    const int* st_g, const int* st_s, const int* st_c,
    const void* tbl, const void* Hm,
    const void* wq, const void* bq, const void* wk, const void* bk,
    const void* wvv, const void* bv, const void* wo, const void* bo,
    const void* w1, const void* b1, const void* g1, const void* be1,
    const void* w2, const void* b2, const void* g2, const void* be2,
    const void* w3, const void* b3, void* outp)
{
    const int b = blockIdx.x;
    const int tid = threadIdx.x;
    const int lane = tid & 63;
    const int wid = __builtin_amdgcn_readfirstlane(tid >> 6);   // 0..7 uniform

    // ---------------- phase 0: H -> fp32 transposed LDS; Xu/Xi embeds ----------------
    for (int i = tid; i < 12 * EE; i += NT) {
        int j = i / EE, e = i - j * EE;
        P.hf[i] = ldf<BF16>(Hm, e * 12 + j);
    }
    if (tid < 80) {
        int f = tid >> 4, e = tid & 15;
        int id = (f == 0) ? uid[b] : (f == 1) ? ut1[b] : (f == 2) ? ut2[b] : (f == 3) ? ut3[b] : ut4[b];
        P.feat[tid] = ldf<BF16>(tbl, id * EMBD + e);
    } else if (tid < 128) {
        int t = tid - 80; int f = t >> 4, e = t & 15;
        int id = (f == 0) ? lb_g[b] : (f == 1) ? lb_s[b] : lb_c[b];
        P.feat[80 + t] = ldf<BF16>(tbl, id * EMBD + e);
    }
    __syncthreads();

    // ---------------- phase 0.5: q projection + item LSH codes (FP order unchanged) --
    if (tid < 32) {
        float acc = ldf<BF16>(bq, tid);
        for (int e = 0; e < EE; e++) acc += P.feat[80 + e] * ldf<BF16>(wq, e * 32 + tid);
        P.q[tid] = acc;
    }
    if (tid >= 64 && tid < 76) {
        int j = tid - 64;
        float acc = 0.f;
        for (int e = 0; e < EE; e++) acc += P.feat[80 + e] * P.hf[j * EE + e];
        P.red[j] = acc;
    }
    __syncthreads();
    if (tid < GG) {
        int code = 0;
        #pragma unroll
        for (int m = 0; m < 3; m++) if (P.red[tid * 3 + m] > 0.f) code |= (1 << m);
        P.icode[tid] = code;
    }

    // ---------------- phase 1: long-term, 4 chunks of 128 positions ----------------
    // phase B work split: wave w covers position block (w&3)*32; lanes 0-31 handle
    // group (w>>2)*2, lanes 32-63 group (w>>2)*2+1. Each thread computes its group's
    // 3 LSH dots with the IDENTICAL k-ascending float4 FP order as before (sign()-safe).
    float accg[GG] = {0.f, 0.f, 0.f, 0.f};     // per-wave selected-bucket sums (lane = e)
    int cnt0 = 0, cnt1 = 0;                     // wave-uniform counts (2 groups per wave)
    const int offs = (lane < 52) ? lane : 51;   // lanes 0..47: data; 48..51: selectors
    const int pB = ((wid & 3) << 5) | (lane & 31);   // position within chunk
    const int gB = ((wid >> 2) << 1) | (lane >> 5);  // LSH group handled by this thread

    for (int ch = 0; ch < LLEN / CHUNK; ch++) {
        const int base = ch * CHUNK;
        // A: pipelined gather: ids -> gathers -> LDS stores (3 jobs/thread @512 threads)
        {
            int ids[3];
            #pragma unroll
            for (int i = 0; i < 3; i++) {
                int f = tid + NT * i;
                int p = f / 12, qq = f - 12 * p, fe = qq >> 2;
                const int* idp = (fe == 0) ? lt_g : (fe == 1) ? lt_s : lt_c;
                ids[i] = idp[b * LLEN + base + p];
            }
            float4 vs[3];
            #pragma unroll
            for (int i = 0; i < 3; i++) {
                int f = tid + NT * i;
                int p = f / 12, qq = f - 12 * p;
                vs[i] = ld4<BF16>(tbl, ids[i] * EMBD + ((qq & 3) << 2));
            }
            #pragma unroll
            for (int i = 0; i < 3; i++) {
                int f = tid + NT * i;
                int p = f / 12, qq = f - 12 * p;
                *(float4*)&P.buf[p * PXE + (qq << 2)] = vs[i];
            }
        }
        __syncthreads();
        // B: LSH codes + selector float for (pB, gB) — all 8 waves busy
        {
            const float* row = &P.buf[pB * PXE];
            float4 x[12];
            #pragma unroll
            for (int k = 0; k < 12; k++) x[k] = *(const float4*)(row + 4 * k);
            float acc[3];
            #pragma unroll
            for (int jj = 0; jj < 3; jj++) {
                const float4* hr = (const float4*)&P.hf[(3 * gB + jj) * EE];
                float s = 0.f;
                #pragma unroll
                for (int k = 0; k < 12; k++) {
                    float4 h4 = hr[k];
                    s += x[k].x * h4.x + x[k].y * h4.y + x[k].z * h4.z + x[k].w * h4.w;
                }
                acc[jj] = s;
            }
            int code = 0;
            #pragma unroll
            for (int m = 0; m < 3; m++) if (acc[m] > 0.f) code |= (1 << m);
            int valid = (lt_g[b * LLEN + base + pB] != 0);
            P.buf[pB * PXE + 48 + gB] = (code == P.icode[gB] && valid) ? 1.f : 0.f;
            // counts include padded positions (ref one-hot semantics)
            unsigned long long m = __ballot(code == P.icode[gB]);
            cnt0 += __popcll(m & 0xFFFFFFFFull);   // lanes 0-31  -> group (wid>>2)*2
            cnt1 += __popcll(m >> 32);             // lanes 32-63 -> group (wid>>2)*2+1
        }
        __syncthreads();
        // C: selected-bucket accumulation — 16 positions per wave, readlane broadcast
        {
            const float* basep = &P.buf[(wid << 4) * PXE] + offs;
            #pragma unroll
            for (int i = 0; i < 16; i++) {
                float xv = basep[i * PXE];
                #pragma unroll
                for (int g = 0; g < GG; g++) {
                    float sel = __int_as_float(
                        __builtin_amdgcn_readlane(__float_as_int(xv), 48 + g));
                    accg[g] += sel * xv;
                }
            }
        }
        __syncthreads();
    }
    // flush partials + counts
    if (lane < EE) {
        #pragma unroll
        for (int g = 0; g < GG; g++) P.part[wid][g][lane] = accg[g];
    }
    if (lane == 0) { P.pcw[wid][0] = cnt0; P.pcw[wid][1] = cnt1; }
    __syncthreads();

    // ---------------- phase 2: long-term interest -> feat[128:176] ----------------
    if (tid < EE) {
        float r = 0.f;
        #pragma unroll
        for (int g = 0; g < GG; g++) {
            int wb = (g >> 1) << 2;       // waves 0-3 hold groups 0,1; waves 4-7 hold 2,3
            int h = g & 1;
            float c = (float)(P.pcw[wb][h] + P.pcw[wb + 1][h] + P.pcw[wb + 2][h] + P.pcw[wb + 3][h]);
            float s = 0.f;
            #pragma unroll
            for (int w = 0; w < 8; w++) s += P.part[w][g][tid];
            r += s / fmaxf(c, 1.0f);      // c==0 => s==0 => 0 (matches ref where())
        }
        P.feat[128 + tid] = r * 0.25f;
    }

    // ---------------- phase 3: short-term attention ----------------
    float* Xs   = P.buf;                 // [64][PXE]
    float* wkq  = P.buf + SLEN * PXE;    // [48][8]
    float* bkq  = wkq + EE * NHH;        // [8]
    float* sc   = bkq + NHH;             // scores/attn, TRANSPOSED: [64][8] = sc[s*8+h]
    float* su   = sc + NHH * SLEN;       // [8][48]
    float* sctx = su + NHH * EE;         // [32]

    {
        // 768 gather jobs: 1 for all threads + a 2nd for tid<256
        int f0 = tid;
        int p0 = f0 / 12, q0 = f0 - 12 * p0, fe0 = q0 >> 2;
        const int* idp0 = (fe0 == 0) ? st_g : (fe0 == 1) ? st_s : st_c;
        int id0 = idp0[b * SLEN + p0];
        int id1 = 0, p1 = 0, q1 = 0;
        bool has1 = (tid < (SLEN * 12 - NT));   // tid < 256
        if (has1) {
            int f1 = tid + NT;
            p1 = f1 / 12; q1 = f1 - 12 * p1; int fe1 = q1 >> 2;
            const int* idp1 = (fe1 == 0) ? st_g : (fe1 == 1) ? st_s : st_c;
            id1 = idp1[b * SLEN + p1];
        }
        float4 v0 = ld4<BF16>(tbl, id0 * EMBD + ((q0 & 3) << 2));
        *(float4*)&Xs[p0 * PXE + (q0 << 2)] = v0;
        if (has1) {
            float4 v1 = ld4<BF16>(tbl, id1 * EMBD + ((q1 & 3) << 2));
            *(float4*)&Xs[p1 * PXE + (q1 << 2)] = v1;
        }
    }
    if (tid < 64) {
        unsigned long long msk = __ballot(st_g[b * SLEN + tid] != 0);
        if (tid == 0) P.len = __popcll(msk);
    }
    for (int t = tid; t < EE * NHH; t += NT) {
        int e = t >> 3, h = t & 7;
        float acc = 0.f;
        #pragma unroll
        for (int d = 0; d < KDD; d++) acc += ldf<BF16>(wk, e * 32 + h * 4 + d) * P.q[h * 4 + d];
        wkq[t] = acc;
    }
    if (tid < NHH) {
        float acc = 0.f;
        #pragma unroll
        for (int d = 0; d < KDD; d++) acc += ldf<BF16>(bk, tid * 4 + d) * P.q[tid * 4 + d];
        bkq[tid] = acc;
    }
    __syncthreads();
    // scores: s = tid>>3, h = tid&7 -> 8 lanes broadcast-share each Xs row (no conflicts);
    // sc stored transposed [s][h] so these writes are lane-consecutive.
    {
        int s = tid >> 3, h = tid & 7;
        float acc = bkq[h];
        for (int e = 0; e < EE; e++) acc += Xs[s * PXE + e] * wkq[e * NHH + h];
        acc *= 0.5f;
        if (s >= P.len) acc -= 1e9f;
        sc[s * NHH + h] = acc;
    }
    __syncthreads();
    // softmax: wave wid handles head wid (8 waves = 8 heads), lane = s
    {
        float v = sc[lane * NHH + wid];
        float mx = v;
        #pragma unroll
        for (int o = 32; o; o >>= 1) mx = fmaxf(mx, __shfl_xor(mx, o));
        float ex = __expf(v - mx);
        float sm = ex;
        #pragma unroll
        for (int o = 32; o; o >>= 1) sm += __shfl_xor(sm, o);
        sc[lane * NHH + wid] = ex / sm;
    }
    __syncthreads();
    if (tid < NHH * EE) {
        int h = tid / EE, e = tid - h * EE;
        float acc = 0.f;
        for (int s = 0; s < SLEN; s++) acc += sc[s * NHH + h] * Xs[s * PXE + e];
        su[tid] = acc;
    }
    __syncthreads();
    if (tid < 32) {
        float acc = ldf<BF16>(bv, tid);
        int h = tid >> 2;
        for (int e = 0; e < EE; e++) acc += su[h * EE + e] * ldf<BF16>(wvv, e * 32 + tid);
        sctx[tid] = acc;
    }
    __syncthreads();
    if (tid < EE) {
        float acc = ldf<BF16>(bo, tid);
        #pragma unroll
        for (int i = 0; i < 32; i++) acc += sctx[i] * ldf<BF16>(wo, i * EE + tid);
        P.feat[176 + tid] = acc;
    }
    __syncthreads();

    // ---------------- phase 4: MLP 224 -> 200(LN,relu) -> 80(LN,relu) -> 1(sigmoid) --
    // z1/z2 input-split across two thread groups to halve the load-FMA chains.
    float z1p = 0.f;
    if (tid < H1D) {
        z1p = ldf<BF16>(b1, tid);
        for (int i = 0; i < 112; i++) z1p += P.feat[i] * ldf<BF16>(w1, i * H1D + tid);
    } else if (tid >= 256 && tid < 256 + H1D) {
        int o = tid - 256;
        float a = 0.f;
        for (int i = 112; i < INDIM; i++) a += P.feat[i] * ldf<BF16>(w1, i * H1D + o);
        P.buf[640 + o] = a;
    }
    __syncthreads();
    float z1 = 0.f;
    if (tid < H1D) { z1 = z1p + P.buf[640 + tid]; P.buf[tid] = z1; }
    __syncthreads();
    if (tid < 64) {
        float sm = 0.f, sq = 0.f;
        for (int j = tid; j < H1D; j += 64) { float v = P.buf[j]; sm += v; sq += v * v; }
        #pragma unroll
        for (int o = 32; o; o >>= 1) { sm += __shfl_xor(sm, o); sq += __shfl_xor(sq, o); }
        if (tid == 0) { float mu = sm / H1D; P.mu = mu; P.rstd = rsqrtf(sq / H1D - mu * mu + 1e-3f); }
    }
    __syncthreads();
    if (tid < H1D) {
        float h = fmaxf(ldf<BF16>(g1, tid) * (z1 - P.mu) * P.rstd + ldf<BF16>(be1, tid), 0.f);
        P.buf[256 + tid] = h;
    }
    __syncthreads();
    float z2p = 0.f;
    if (tid < H2D) {
        z2p = ldf<BF16>(b2, tid);
        for (int i = 0; i < 100; i++) z2p += P.buf[256 + i] * ldf<BF16>(w2, i * H2D + tid);
    } else if (tid >= 256 && tid < 256 + H2D) {
        int o = tid - 256;
        float a = 0.f;
        for (int i = 100; i < H1D; i++) a += P.buf[256 + i] * ldf<BF16>(w2, i * H2D + o);
        P.buf[640 + o] = a;
    }
    __syncthreads();
    float z2 = 0.f;
    if (tid < H2D) { z2 = z2p + P.buf[640 + tid]; P.buf[tid] = z2; }
    __syncthreads();
    if (tid < 64) {
        float sm = 0.f, sq = 0.f;
        for (int j = tid; j < H2D; j += 64) { float v = P.buf[j]; sm += v; sq += v * v; }
        #pragma unroll
        for (int o = 32; o; o >>= 1) { sm += __shfl_xor(sm, o); sq += __shfl_xor(sq, o); }
        if (tid == 0) { float mu = sm / H2D; P.mu = mu; P.rstd = rsqrtf(sq / H2D - mu * mu + 1e-3f); }
    }
    __syncthreads();
    if (tid < H2D) {
        float h = fmaxf(ldf<BF16>(g2, tid) * (z2 - P.mu) * P.rstd + ldf<BF16>(be2, tid), 0.f);
        P.red[tid] = h * ldf<BF16>(w3, tid);
    }
    __syncthreads();
    if (tid < 64) {
        float v = P.red[tid] + ((tid < H2D - 64) ? P.red[64 + tid] : 0.f);
        #pragma unroll
        for (int o = 32; o; o >>= 1) v += __shfl_xor(v, o);
        if (tid == 0) {
            float acc = ldf<BF16>(b3, 0) + v;
            float sig = 1.f / (1.f + __expf(-acc));
            if constexpr (BF16) ((__hip_bfloat16*)outp)[b] = __float2bfloat16(sig);
            else                ((float*)outp)[b] = sig;
        }
    }
}

__global__ __launch_bounds__(NT, 8) void sdim_fwd(
    const int* __restrict__ uid, const int* __restrict__ ut1, const int* __restrict__ ut2,
    const int* __restrict__ ut3, const int* __restrict__ ut4,
    const int* __restrict__ lb_g, const int* __restrict__ lb_s, const int* __restrict__ lb_c,
    const int* __restrict__ lt_g, const int* __restrict__ lt_s, const int* __restrict__ lt_c,
    const int* __restrict__ st_g, const int* __restrict__ st_s, const int* __restrict__ st_c,
    const void* __restrict__ tbl, const void* __restrict__ Hm,
    const void* __restrict__ wq, const void* __restrict__ bq,
    const void* __restrict__ wk, const void* __restrict__ bk,
    const void* __restrict__ wvv, const void* __restrict__ bv,
    const void* __restrict__ wo, const void* __restrict__ bo,
    const void* __restrict__ w1, const void* __restrict__ b1,
    const void* __restrict__ g1, const void* __restrict__ be1,
    const void* __restrict__ w2, const void* __restrict__ b2,
    const void* __restrict__ g2, const void* __restrict__ be2,
    const void* __restrict__ w3, const void* __restrict__ b3,
    void* __restrict__ outp)
{
    __shared__ Pool P;
    __shared__ int s_isbf;
    // in-block dtype detection: even ushort indices of bf16 data are small values
    // (exp<127); of fp32 they are random mantissa bits (P[all 128 exp<127] ~ 2^-128)
    if (threadIdx.x < 64) {
        int big = 0;
        for (int i = (threadIdx.x & 63); i < 128; i += 64) {
            unsigned short u = ((const unsigned short*)tbl)[2 * i];
            if (((u >> 7) & 0xFF) >= 127) big = 1;
        }
        unsigned long long m = __ballot(big);
        if (threadIdx.x == 0) s_isbf = (m == 0ull) ? 1 : 0;
    }
    __syncthreads();
    if (s_isbf)
        sdim_body<true >(P, uid, ut1, ut2, ut3, ut4, lb_g, lb_s, lb_c, lt_g, lt_s, lt_c,
                         st_g, st_s, st_c, tbl, Hm, wq, bq, wk, bk, wvv, bv, wo, bo,
                         w1, b1, g1, be1, w2, b2, g2, be2, w3, b3, outp);
    else
        sdim_body<false>(P, uid, ut1, ut2, ut3, ut4, lb_g, lb_s, lb_c, lt_g, lt_s, lt_c,
                         st_g, st_s, st_c, tbl, Hm, wq, bq, wk, bk, wvv, bv, wo, bo,
                         w1, b1, g1, be1, w2, b2, g2, be2, w3, b3, outp);
}

extern "C" void kernel_launch(void* const* d_in, const int* in_sizes, int n_in,
                              void* d_out, int out_size, void* d_ws, size_t ws_size,
                              hipStream_t stream) {
    const int B = in_sizes[0];   // batch = 1024
    sdim_fwd<<<B, NT, 0, stream>>>(
        (const int*)d_in[0],  (const int*)d_in[1],  (const int*)d_in[2],
        (const int*)d_in[3],  (const int*)d_in[4],
        (const int*)d_in[5],  (const int*)d_in[6],  (const int*)d_in[7],
        (const int*)d_in[8],  (const int*)d_in[9],  (const int*)d_in[10],
        (const int*)d_in[11], (const int*)d_in[12], (const int*)d_in[13],
        (const void*)d_in[14], (const void*)d_in[15],
        (const void*)d_in[16], (const void*)d_in[17],
        (const void*)d_in[18], (const void*)d_in[19],
        (const void*)d_in[20], (const void*)d_in[21],
        (const void*)d_in[22], (const void*)d_in[23],
        (const void*)d_in[24], (const void*)d_in[25],
        (const void*)d_in[26], (const void*)d_in[27],
        (const void*)d_in[28], (const void*)d_in[29],
        (const void*)d_in[30], (const void*)d_in[31],
        (const void*)d_in[32], (const void*)d_in[33],
        d_out);
}